// Round 5
// baseline (138.174 us; speedup 1.0000x reference)
//
#include <hip/hip_runtime.h>
#include <hip/hip_bf16.h>

// Problem constants
#define B_   32
#define N_   128
#define KNB  16
#define C_   1024
#define KER  8
#define DOUT 128      // OUT/KERNEL
#define OUTC 1024
#define BK   64
#define NT   (C_ / BK)     // 16 K-steps
#define HCOL 64            // G-columns per block (half of DOUT)

typedef __attribute__((ext_vector_type(8))) short bf16x8;
typedef __attribute__((ext_vector_type(4))) float f32x4;

__device__ __forceinline__ ushort f2bf(float f) {
    unsigned u = __builtin_bit_cast(unsigned, f);
    unsigned r = (u + 0x7FFFu + ((u >> 16) & 1u)) >> 16;
    return (ushort)r;
}

#define GLOAD_LDS16(gp, lp)                                                    \
    __builtin_amdgcn_global_load_lds(                                          \
        (__attribute__((address_space(1))) void*)(gp),                         \
        (__attribute__((address_space(3))) void*)(lp), 16, 0, 0)

// ---------------------------------------------------------------------------
// Prep kernel: blocks [0,1024): transpose conv_w [KER][C][DOUT] -> WbT bf16
//              blocks [1024,1280): edge weights ew[b][n][k][m]
// ---------------------------------------------------------------------------
__global__ __launch_bounds__(256) void k_prep(const float* __restrict__ cw,
                                              ushort* __restrict__ WbT,
                                              const float* __restrict__ centre,
                                              const int* __restrict__ nidx,
                                              const float* __restrict__ gw,
                                              const float* __restrict__ mr,
                                              const float* __restrict__ mt,
                                              const float* __restrict__ pr,
                                              const float* __restrict__ pt,
                                              float* __restrict__ ew) {
    __shared__ float tile[32][33];
    int bid = blockIdx.x;
    int tid = threadIdx.x;
    if (bid < 1024) {
        int dt = bid & 3;
        int ct = (bid >> 2) & 31;
        int m  = bid >> 7;
        int tx = tid & 31;
        int ty = tid >> 5;
#pragma unroll
        for (int i = 0; i < 4; ++i) {
            int cr = ty + i * 8;
            tile[cr][tx] = cw[((size_t)m * C_ + (ct * 32 + cr)) * DOUT + dt * 32 + tx];
        }
        __syncthreads();
#pragma unroll
        for (int i = 0; i < 4; ++i) {
            int dr = ty + i * 8;
            WbT[((size_t)(m * DOUT + dt * 32 + dr)) * C_ + ct * 32 + tx] = f2bf(tile[tx][dr]);
        }
    } else {
        int t = (bid - 1024) * 256 + tid;        // 65536 = B*N*K
        int bn = t >> 4;
        int b  = bn >> 7;
        float2 ci = *(const float2*)(centre + (size_t)bn * 2);
        int j = nidx[t];
        float2 cj = *(const float2*)(centre + (size_t)(b * N_ + j) * 2);
        float cx = ci.x - cj.x, cy = ci.y - cj.y;
        float rho = sqrtf(cx * cx + cy * cy);
        float theta = atan2f(cx, cy);            // atan2(x, y) per reference
        float w[KER];
        float sum = 0.f;
#pragma unroll
        for (int m = 0; m < KER; ++m) {
            float dr = rho - mr[m];
            float wr = expf(-0.5f * dr * dr / (1e-14f + pr[m] * pr[m]));
            float a1 = fabsf(theta - mt[m]);
            float a2 = fabsf(6.2831853071795864f - a1);
            float am = fminf(a1, a2);
            float wt = expf(-0.5f * am * am / (1e-14f + pt[m] * pt[m]));
            float wv = wr * wt;
            if (isnan(wv)) wv = 0.f;
            w[m] = wv;
            sum += wv;
        }
        float scale = gw[t] / sum;
#pragma unroll
        for (int m = 0; m < KER; ++m) ew[(size_t)t * KER + m] = w[m] * scale;
    }
}

// ---------------------------------------------------------------------------
// Fused kernel, block (b, y=m*2+h): computes G-columns [m*128+h*64, +64):
//   Gt[128][64] = f32(F_b) x WbT[m*128+h*64 .. +64]^T  (A f32->bf16 in-kernel)
//   out[b][n][m*128+h*64+d] = relu( sum_k ew[b][n][k][m] * Gt[j[n][k]][d] )
// 512 blocks (2/CU), 8 waves (4x2). A reg-staged, B global_load_lds.
// Double-buffered, one barrier/K-step, counted vmcnt(4). XOR chunk swizzle.
// ---------------------------------------------------------------------------
__global__ __launch_bounds__(512, 4) void k_fused(const float* __restrict__ F,
                                                  const ushort* __restrict__ WbT,
                                                  const float* __restrict__ ew,
                                                  const int* __restrict__ nidx,
                                                  float* __restrict__ out) {
    // staging: 2 bufs x (A 16KB + B 8KB) = 48KB; Gt f32 [128][66] = 33792 B
    __shared__ __align__(16) char smem[49152];

    int tid  = threadIdx.x;
    int wave = tid >> 6;
    int lane = tid & 63;
    int wm = wave >> 1;            // 0..3 (32-row stripe)
    int wn = wave & 1;             // 0..1 (32-col stripe of the 64)
    int lr = lane & 15;
    int kg = lane >> 4;
    int b = blockIdx.x;
    int y = blockIdx.y;            // m*2 + h
    int m = y >> 1, h = y & 1;

    const float*  Af = F   + (size_t)b * N_ * C_;
    const ushort* Bb = WbT + (size_t)(m * DOUT + h * HCOL) * C_;

    // ---- gather metadata prefetch (drains inside prologue's counted waits)
    int n = tid >> 2, q = tid & 3;
    const int* ip = nidx + (size_t)(b * N_ + n) * KNB;
    int4 jv0 = *(const int4*)(ip);
    int4 jv1 = *(const int4*)(ip + 4);
    int4 jv2 = *(const int4*)(ip + 8);
    int4 jv3 = *(const int4*)(ip + 12);
    const float* ep = ew + (size_t)(b * N_ + n) * (KNB * KER) + m;
    float wv[KNB];
#pragma unroll
    for (int k = 0; k < KNB; ++k) wv[k] = ep[k * KER];

    // A reg-stage mapping: row = tid>>2, 16-col quarter qq = tid&3
    int arow = tid >> 2, qq = tid & 3;
    const float* asrc = Af + (size_t)arow * C_ + qq * 16;
    int as0 = ((qq * 2)     ^ (arow & 7)) * 8 + arow * 64;   // ushort offsets
    int as1 = ((qq * 2 + 1) ^ (arow & 7)) * 8 + arow * 64;

    f32x4 acc[2][2];
#pragma unroll
    for (int i = 0; i < 2; ++i)
#pragma unroll
        for (int j = 0; j < 2; ++j) acc[i][j] = (f32x4){0.f, 0.f, 0.f, 0.f};

    f32x4 areg[4];

    // fragment byte offsets (buffer-relative), swizzled read side
    int aoff[2][2], boff[2][2];
#pragma unroll
    for (int mi = 0; mi < 2; ++mi)
#pragma unroll
        for (int kk = 0; kk < 2; ++kk) {
            int row = wm * 32 + mi * 16 + lr;
            int ch  = (kk * 4 + kg) ^ (row & 7);
            aoff[mi][kk] = row * 128 + ch * 16;
        }
#pragma unroll
    for (int ni = 0; ni < 2; ++ni)
#pragma unroll
        for (int kk = 0; kk < 2; ++kk) {
            int row = wn * 32 + ni * 16 + lr;           // 0..63 (B tile rows)
            int ch  = (kk * 4 + kg) ^ (row & 7);
            boff[ni][kk] = 16384 + row * 128 + ch * 16;
        }

    auto A_ISSUE = [&](int kt) {
#pragma unroll
        for (int i = 0; i < 4; ++i)
            areg[i] = *(const f32x4*)(asrc + kt * BK + i * 4);
    };
    auto A_WRITE = [&](int buf) {
        ushort* As = (ushort*)(smem + buf * 24576);
        bf16x8 w0, w1;
#pragma unroll
        for (int i = 0; i < 2; ++i)
#pragma unroll
            for (int j = 0; j < 4; ++j) w0[i * 4 + j] = (short)f2bf(areg[i][j]);
#pragma unroll
        for (int i = 0; i < 2; ++i)
#pragma unroll
            for (int j = 0; j < 4; ++j) w1[i * 4 + j] = (short)f2bf(areg[2 + i][j]);
        *(bf16x8*)(As + as0) = w0;
        *(bf16x8*)(As + as1) = w1;
    };
    auto B_ISSUE = [&](int buf, int kt) {
        ushort* Bs = (ushort*)(smem + buf * 24576 + 16384);
        int segb = wave * 64;                 // wave-uniform LDS base (512 segs)
        int seg  = segb + lane;
        int row  = seg >> 3;                  // 0..63
        int ch   = (seg & 7) ^ (row & 7);
        const ushort* gb = Bb + (size_t)row * C_ + kt * BK + ch * 8;
        GLOAD_LDS16(gb, Bs + segb * 8);
    };

    // ---- prologue (prefetches above are oldest; drained by A_WRITE's wait)
    A_ISSUE(0);                   // A(0) -> regs (4 loads)
    B_ISSUE(0, 0);                // B(0) in flight (1)
    A_WRITE(0);                   // waits A(0); B(0) stays
    A_ISSUE(1);                   // A(1) in flight (4)
    asm volatile("s_waitcnt vmcnt(4)" ::: "memory");    // drain B(0), keep A(1)
    asm volatile("s_waitcnt lgkmcnt(0)" ::: "memory");  // A(0) LDS writes visible
    __builtin_amdgcn_s_barrier();

    for (int kt = 0; kt < NT; ++kt) {
        int cur = kt & 1;
        const char* bufp = smem + cur * 24576;
        if (kt + 1 < NT) {
            A_WRITE(cur ^ 1);          // waits A(kt+1) regs; writes other buf
            B_ISSUE(cur ^ 1, kt + 1);  // B(kt+1) in flight (1, oldest)
        }
        if (kt + 2 < NT) A_ISSUE(kt + 2);   // A(kt+2) in flight (4, youngest)

#pragma unroll
        for (int kk = 0; kk < 2; ++kk) {
            bf16x8 af[2], bv[2];
#pragma unroll
            for (int mi = 0; mi < 2; ++mi)
                af[mi] = *(const bf16x8*)(bufp + aoff[mi][kk]);
#pragma unroll
            for (int ni = 0; ni < 2; ++ni)
                bv[ni] = *(const bf16x8*)(bufp + boff[ni][kk]);
#pragma unroll
            for (int mi = 0; mi < 2; ++mi)
#pragma unroll
                for (int ni = 0; ni < 2; ++ni)
                    acc[mi][ni] = __builtin_amdgcn_mfma_f32_16x16x32_bf16(
                        af[mi], bv[ni], acc[mi][ni], 0, 0, 0);
        }

        if (kt + 1 < NT) {
            if (kt + 2 < NT)
                asm volatile("s_waitcnt vmcnt(4)" ::: "memory");  // drain B(kt+1)
            else
                asm volatile("s_waitcnt vmcnt(0)" ::: "memory");  // tail drain
            asm volatile("s_waitcnt lgkmcnt(0)" ::: "memory");    // A writes visible
            __builtin_amdgcn_s_barrier();
        }
    }

    // ---- epilogue: acc -> Gt LDS (f32 [128][66])
    __syncthreads();                              // all staging reads done
    float* Gt = (float*)smem;
#pragma unroll
    for (int mi = 0; mi < 2; ++mi)
#pragma unroll
        for (int ni = 0; ni < 2; ++ni)
#pragma unroll
            for (int r = 0; r < 4; ++r) {
                int grow = wm * 32 + mi * 16 + kg * 4 + r;   // C/D: row=kg*4+r
                int gcol = wn * 32 + ni * 16 + lr;           //      col=lane&15
                Gt[grow * 66 + gcol] = acc[mi][ni][r];
            }
    __syncthreads();

    // ---- gather: thread = (row n = tid>>2, quarter q = tid&3, 16 cols)
    // per-q rotation spreads banks; rows add 2n mod 32 spread.
    int rot[4];
#pragma unroll
    for (int i = 0; i < 4; ++i) rot[i] = (q * 4 + i * 4) & 15;
    f32x4 o[4];
#pragma unroll
    for (int i = 0; i < 4; ++i) o[i] = (f32x4){0.f, 0.f, 0.f, 0.f};
    int jarr[KNB] = {jv0.x, jv0.y, jv0.z, jv0.w, jv1.x, jv1.y, jv1.z, jv1.w,
                     jv2.x, jv2.y, jv2.z, jv2.w, jv3.x, jv3.y, jv3.z, jv3.w};
#pragma unroll
    for (int k = 0; k < KNB; ++k) {
        const float* gr = Gt + jarr[k] * 66 + q * 16;
        float w = wv[k];
#pragma unroll
        for (int i = 0; i < 4; ++i) {
            f32x4 v = *(const f32x4*)(gr + rot[i]);
            o[i] += v * w;
        }
    }
    float* op = out + (size_t)(b * N_ + n) * OUTC + m * DOUT + h * HCOL + q * 16;
#pragma unroll
    for (int i = 0; i < 4; ++i) {
        f32x4 r = o[i];
#pragma unroll
        for (int jj = 0; jj < 4; ++jj) r[jj] = fmaxf(r[jj], 0.f);
        *(f32x4*)(op + rot[i]) = r;
    }
}

// ---------------------------------------------------------------------------
extern "C" void kernel_launch(void* const* d_in, const int* in_sizes, int n_in,
                              void* d_out, int out_size, void* d_ws, size_t ws_size,
                              hipStream_t stream) {
    const float* node_feats      = (const float*)d_in[0];
    const float* node_centre     = (const float*)d_in[1];
    const int*   neighbor_idx    = (const int*)d_in[2];
    const float* graph_weights   = (const float*)d_in[3];
    const float* mean_rho        = (const float*)d_in[4];
    const float* mean_theta      = (const float*)d_in[5];
    const float* precision_rho   = (const float*)d_in[6];
    const float* precision_theta = (const float*)d_in[7];
    const float* conv_w          = (const float*)d_in[8];
    float* out = (float*)d_out;

    char* ws = (char*)d_ws;
    ushort* WbT = (ushort*)(ws);                   // 2 MB
    float*  ew  = (float*) (ws + (2u << 20));      // 2 MB

    k_prep<<<1280, 256, 0, stream>>>(conv_w, WbT,
                                     node_centre, neighbor_idx, graph_weights,
                                     mean_rho, mean_theta,
                                     precision_rho, precision_theta, ew);
    dim3 ggrid(B_, KER * 2);   // 512 blocks: (batch, m*2+half)
    k_fused<<<ggrid, 512, 0, stream>>>(node_feats, WbT, ew, neighbor_idx, out);
}

// Round 6
// 130.822 us; speedup vs baseline: 1.0562x; 1.0562x over previous
//
#include <hip/hip_runtime.h>
#include <hip/hip_bf16.h>

// Problem constants
#define B_   32
#define N_   128
#define KNB  16
#define C_   1024
#define KER  8
#define DOUT 128      // OUT/KERNEL
#define OUTC 1024

typedef __attribute__((ext_vector_type(8))) short bf16x8;
typedef __attribute__((ext_vector_type(4))) float f32x4;

__device__ __forceinline__ ushort f2bf(float f) {
    unsigned u = __builtin_bit_cast(unsigned, f);
    unsigned r = (u + 0x7FFFu + ((u >> 16) & 1u)) >> 16;
    return (ushort)r;
}

// ---------------------------------------------------------------------------
// Prep kernel (merged): blocks [0,4096): convert node_feats f32->bf16
//                       blocks [4096,5120): transpose conv_w -> WbT bf16
//                       blocks [5120,5376): edge weights
// ---------------------------------------------------------------------------
__global__ __launch_bounds__(256) void k_prep(const float* __restrict__ f,
                                              ushort* __restrict__ Fb,
                                              const float* __restrict__ cw,
                                              ushort* __restrict__ WbT,
                                              const float* __restrict__ centre,
                                              const int* __restrict__ nidx,
                                              const float* __restrict__ gw,
                                              const float* __restrict__ mr,
                                              const float* __restrict__ mt,
                                              const float* __restrict__ pr,
                                              const float* __restrict__ pt,
                                              float* __restrict__ ew) {
    __shared__ float tile[32][33];
    int bid = blockIdx.x;
    int tid = threadIdx.x;
    if (bid < 4096) {
        // ---- convert: 1M threads x 4 elems
        int t = bid * 256 + tid;
        float4 v = ((const float4*)f)[t];
        ushort4 o;
        o.x = f2bf(v.x); o.y = f2bf(v.y); o.z = f2bf(v.z); o.w = f2bf(v.w);
        ((ushort4*)Fb)[t] = o;
    } else if (bid < 5120) {
        // ---- transpose conv_w [KER][C][DOUT] -> WbT [KER*DOUT][C]
        int b2 = bid - 4096;
        int dt = b2 & 3;
        int ct = (b2 >> 2) & 31;
        int m  = b2 >> 7;
        int tx = tid & 31;
        int ty = tid >> 5;
#pragma unroll
        for (int i = 0; i < 4; ++i) {
            int cr = ty + i * 8;
            tile[cr][tx] = cw[((size_t)m * C_ + (ct * 32 + cr)) * DOUT + dt * 32 + tx];
        }
        __syncthreads();
#pragma unroll
        for (int i = 0; i < 4; ++i) {
            int dr = ty + i * 8;
            WbT[((size_t)(m * DOUT + dt * 32 + dr)) * C_ + ct * 32 + tx] = f2bf(tile[tx][dr]);
        }
    } else {
        // ---- edge weights: 65536 threads = B*N*K
        int t = (bid - 5120) * 256 + tid;
        int bn = t >> 4;
        int b  = bn >> 7;
        float2 ci = *(const float2*)(centre + (size_t)bn * 2);
        int j = nidx[t];
        float2 cj = *(const float2*)(centre + (size_t)(b * N_ + j) * 2);
        float cx = ci.x - cj.x, cy = ci.y - cj.y;
        float rho = sqrtf(cx * cx + cy * cy);
        float theta = atan2f(cx, cy);            // atan2(x, y) per reference
        float w[KER];
        float sum = 0.f;
#pragma unroll
        for (int m = 0; m < KER; ++m) {
            float dr = rho - mr[m];
            float wr = expf(-0.5f * dr * dr / (1e-14f + pr[m] * pr[m]));
            float a1 = fabsf(theta - mt[m]);
            float a2 = fabsf(6.2831853071795864f - a1);
            float am = fminf(a1, a2);
            float wt = expf(-0.5f * am * am / (1e-14f + pt[m] * pt[m]));
            float wv = wr * wt;
            if (isnan(wv)) wv = 0.f;
            w[m] = wv;
            sum += wv;
        }
        float scale = gw[t] / sum;
#pragma unroll
        for (int m = 0; m < KER; ++m) ew[(size_t)t * KER + m] = w[m] * scale;
    }
}

// ---------------------------------------------------------------------------
// Fused kernel, block bid: b = bid&31, m = bid>>5  (XCD = bid%8 = b%8 ->
// all 8 m-blocks of a batch share one XCD's L2 for the F panel).
//   Gt[128][128] = Fb_b (128x1024) x WbT_m^T   via split-K across waves:
//   wave (kq,rh,ch): partial sum over K-half kq*512 for sub-tile
//   (rows rh*64..+64, cols ch*64..+64). MFMA fragments loaded DIRECTLY from
//   global (no LDS staging, no barriers, no manual waitcnt in main loop).
//   Epilogue: kq=0 writes Gt, kq=1 accumulates; then fused gather+ReLU.
// ---------------------------------------------------------------------------
__global__ __launch_bounds__(512, 2) void k_fused(const ushort* __restrict__ Fb,
                                                  const ushort* __restrict__ WbT,
                                                  const float* __restrict__ ew,
                                                  const int* __restrict__ nidx,
                                                  float* __restrict__ out) {
    __shared__ float Gt[128 * 132];               // 67584 B

    int tid  = threadIdx.x;
    int wave = tid >> 6;
    int lane = tid & 63;
    int kq = wave >> 2;            // K-half (0,1)
    int rh = (wave >> 1) & 1;      // 64-row half
    int ch = wave & 1;             // 64-col half
    int lr = lane & 15;
    int kg = lane >> 4;
    int bid = blockIdx.x;
    int b = bid & 31;
    int m = bid >> 5;

    // fragment base addresses (per-lane): row (rh*64 + mi*16 + lr), k (kq*512 + s*32 + kg*8)
    const ushort* Ab = Fb  + ((size_t)(b * N_ + rh * 64 + lr)) * C_ + kq * 512 + kg * 8;
    const ushort* Bb = WbT + ((size_t)(m * DOUT + ch * 64 + lr)) * C_ + kq * 512 + kg * 8;

    f32x4 acc[4][4];
#pragma unroll
    for (int i = 0; i < 4; ++i)
#pragma unroll
        for (int j = 0; j < 4; ++j) acc[i][j] = (f32x4){0.f, 0.f, 0.f, 0.f};

    // ---- main loop: 16 steps x {8 x 16B direct frag loads + 16 MFMA}, no sync
#pragma unroll
    for (int s = 0; s < 16; ++s) {
        bf16x8 av[4], bv[4];
#pragma unroll
        for (int i = 0; i < 4; ++i) {
            av[i] = *(const bf16x8*)(Ab + (size_t)i * 16 * C_ + s * 32);
            bv[i] = *(const bf16x8*)(Bb + (size_t)i * 16 * C_ + s * 32);
        }
#pragma unroll
        for (int mi = 0; mi < 4; ++mi)
#pragma unroll
            for (int nj = 0; nj < 4; ++nj)
                acc[mi][nj] = __builtin_amdgcn_mfma_f32_16x16x32_bf16(
                    av[mi], bv[nj], acc[mi][nj], 0, 0, 0);
    }

    // ---- gather metadata prefetch (overlaps other waves' tail work)
    int n = tid >> 2, q = tid & 3;
    const int* ip = nidx + (size_t)(b * N_ + n) * KNB;
    int4 jv0 = *(const int4*)(ip);
    int4 jv1 = *(const int4*)(ip + 4);
    int4 jv2 = *(const int4*)(ip + 8);
    int4 jv3 = *(const int4*)(ip + 12);
    const float* ep = ew + (size_t)(b * N_ + n) * (KNB * KER) + m;
    float wv[KNB];
#pragma unroll
    for (int k = 0; k < KNB; ++k) wv[k] = ep[k * KER];

    // ---- split-K reduction into Gt (C/D layout: row=kg*4+r, col=lane&15)
    if (kq == 0) {
#pragma unroll
        for (int mi = 0; mi < 4; ++mi)
#pragma unroll
            for (int nj = 0; nj < 4; ++nj)
#pragma unroll
                for (int r = 0; r < 4; ++r) {
                    int grow = rh * 64 + mi * 16 + kg * 4 + r;
                    int gcol = ch * 64 + nj * 16 + lr;
                    Gt[grow * 132 + gcol] = acc[mi][nj][r];
                }
    }
    __syncthreads();
    if (kq == 1) {
#pragma unroll
        for (int mi = 0; mi < 4; ++mi)
#pragma unroll
            for (int nj = 0; nj < 4; ++nj)
#pragma unroll
                for (int r = 0; r < 4; ++r) {
                    int grow = rh * 64 + mi * 16 + kg * 4 + r;
                    int gcol = ch * 64 + nj * 16 + lr;
                    Gt[grow * 132 + gcol] += acc[mi][nj][r];
                }
    }
    __syncthreads();

    // ---- gather + ReLU: thread = (row n = tid>>2, quarter q = tid&3, 32 cols)
    int rot[8];
#pragma unroll
    for (int i = 0; i < 8; ++i) rot[i] = (q * 4 + i * 4) & 31;
    f32x4 o[8];
#pragma unroll
    for (int i = 0; i < 8; ++i) o[i] = (f32x4){0.f, 0.f, 0.f, 0.f};
    int jarr[KNB] = {jv0.x, jv0.y, jv0.z, jv0.w, jv1.x, jv1.y, jv1.z, jv1.w,
                     jv2.x, jv2.y, jv2.z, jv2.w, jv3.x, jv3.y, jv3.z, jv3.w};
#pragma unroll
    for (int k = 0; k < KNB; ++k) {
        const float* gr = Gt + jarr[k] * 132 + q * 32;
        float w = wv[k];
#pragma unroll
        for (int i = 0; i < 8; ++i) {
            f32x4 v = *(const f32x4*)(gr + rot[i]);
            o[i] += v * w;
        }
    }
    float* op = out + (size_t)(b * N_ + n) * OUTC + m * DOUT + q * 32;
#pragma unroll
    for (int i = 0; i < 8; ++i) {
        f32x4 r = o[i];
#pragma unroll
        for (int jj = 0; jj < 4; ++jj) r[jj] = fmaxf(r[jj], 0.f);
        *(f32x4*)(op + rot[i]) = r;
    }
}

// ---------------------------------------------------------------------------
extern "C" void kernel_launch(void* const* d_in, const int* in_sizes, int n_in,
                              void* d_out, int out_size, void* d_ws, size_t ws_size,
                              hipStream_t stream) {
    const float* node_feats      = (const float*)d_in[0];
    const float* node_centre     = (const float*)d_in[1];
    const int*   neighbor_idx    = (const int*)d_in[2];
    const float* graph_weights   = (const float*)d_in[3];
    const float* mean_rho        = (const float*)d_in[4];
    const float* mean_theta      = (const float*)d_in[5];
    const float* precision_rho   = (const float*)d_in[6];
    const float* precision_theta = (const float*)d_in[7];
    const float* conv_w          = (const float*)d_in[8];
    float* out = (float*)d_out;

    char* ws = (char*)d_ws;
    ushort* Fb  = (ushort*)(ws);                   // 8 MB
    ushort* WbT = (ushort*)(ws + (8u  << 20));     // 2 MB
    float*  ew  = (float*) (ws + (10u << 20));     // 2 MB

    k_prep<<<5376, 256, 0, stream>>>(node_feats, Fb, conv_w, WbT,
                                     node_centre, neighbor_idx, graph_weights,
                                     mean_rho, mean_theta,
                                     precision_rho, precision_theta, ew);
    // 256 blocks; bid = m*32 + b so all 8 m-blocks of a batch land on one XCD
    k_fused<<<256, 512, 0, stream>>>(Fb, WbT, ew, neighbor_idx, out);
}

// Round 8
// 108.058 us; speedup vs baseline: 1.2787x; 1.2107x over previous
//
#include <hip/hip_runtime.h>
#include <hip/hip_bf16.h>

// Problem constants
#define B_   32
#define N_   128
#define KNB  16
#define C_   1024
#define KER  8
#define DOUT 128      // OUT/KERNEL
#define OUTC 1024

typedef __attribute__((ext_vector_type(8))) short bf16x8;
typedef __attribute__((ext_vector_type(4))) float f32x4;

__device__ __forceinline__ ushort f2bf(float f) {
    unsigned u = __builtin_bit_cast(unsigned, f);
    unsigned r = (u + 0x7FFFu + ((u >> 16) & 1u)) >> 16;
    return (ushort)r;
}

// Fragment-packed layouts (ushort units):
//   Fpack[b][rh][mi][kq][s][lane][8] : strides  b:131072 rh:65536 mi:16384
//                                      kq:8192 s:512 lane:8
//   value = F[b*128 + rh*64 + mi*16 + (lane&15)][kq*512 + s*32 + (lane>>4)*8 + j]
//   Wpack[m][ch][nj][kq][s][lane][8] : same strides with m:131072 ch:65536 nj:16384
//   value = conv_w[m][kq*512 + s*32 + (lane>>4)*8 + j][ch*64 + nj*16 + (lane&15)]

// ---------------------------------------------------------------------------
// Prep kernel: blocks [0,256):   A-pack  (b,rh,mi) -> Fpack
//              blocks [256,320): W-pack  (m,ch,nj) -> Wpack
//              blocks [320,576): edge weights ew
// ---------------------------------------------------------------------------
__global__ __launch_bounds__(256) void k_prep(const float* __restrict__ F,
                                              ushort* __restrict__ Fpack,
                                              const float* __restrict__ W,
                                              ushort* __restrict__ Wpack,
                                              const float* __restrict__ centre,
                                              const int* __restrict__ nidx,
                                              const float* __restrict__ gw,
                                              const float* __restrict__ mr,
                                              const float* __restrict__ mt,
                                              const float* __restrict__ pr,
                                              const float* __restrict__ pt,
                                              float* __restrict__ ew) {
    __shared__ ushort Pt[16 * 1032];          // 33 KB padded tile [16][1032]
    int bid = blockIdx.x;
    int t   = threadIdx.x;

    if (bid < 256) {
        // ---- A-pack: block = (b, rh, mi); 16 rows x 1024 k
        int R0 = bid * 16;                    // global row (b*128+rh*64+mi*16)
        // read pass: one row per iter, fully coalesced float4
#pragma unroll
        for (int it = 0; it < 16; ++it) {
            float4 v = *(const float4*)(F + (size_t)(R0 + it) * C_ + t * 4);
            ushort* d = Pt + it * 1032 + t * 4;
            d[0] = f2bf(v.x); d[1] = f2bf(v.y); d[2] = f2bf(v.z); d[3] = f2bf(v.w);
        }
        __syncthreads();
        // write pass: chunk c = it*256+t in [0,2048); lane=c&63, s=(c>>6)&15, kq=c>>10
        ushort* dst = Fpack + (size_t)bid * 16384;
#pragma unroll
        for (int it = 0; it < 8; ++it) {
            int c  = it * 256 + t;
            int ln = c & 63, s = (c >> 6) & 15, kq = c >> 10;
            int lr = ln & 15, kg = ln >> 4;
            bf16x8 v = *(const bf16x8*)(Pt + lr * 1032 + kq * 512 + s * 32 + kg * 8);
            *(bf16x8*)(dst + (size_t)c * 8) = v;
        }
    } else if (bid < 320) {
        // ---- W-pack: block = (m, ch, nj); 1024 c x 16 d slice
        int b2 = bid - 256;                   // m*8 + ch*4 + nj
        int m  = b2 >> 3;
        int D0 = ((b2 >> 2) & 1) * 64 + (b2 & 3) * 16;
        // read pass: f = it*256+t in [0,4096): c = f>>2, q4 = f&3
#pragma unroll
        for (int it = 0; it < 16; ++it) {
            int f  = it * 256 + t;
            int c  = f >> 2, q4 = f & 3;
            float4 v = *(const float4*)(W + (size_t)m * (C_ * DOUT) + (size_t)c * DOUT + D0 + q4 * 4);
            Pt[(q4 * 4 + 0) * 1032 + c] = f2bf(v.x);
            Pt[(q4 * 4 + 1) * 1032 + c] = f2bf(v.y);
            Pt[(q4 * 4 + 2) * 1032 + c] = f2bf(v.z);
            Pt[(q4 * 4 + 3) * 1032 + c] = f2bf(v.w);
        }
        __syncthreads();
        // write pass: identical chunk mapping (row = d-lane, col = k)
        ushort* dst = Wpack + (size_t)b2 * 16384;
#pragma unroll
        for (int it = 0; it < 8; ++it) {
            int c  = it * 256 + t;
            int ln = c & 63, s = (c >> 6) & 15, kq = c >> 10;
            int lr = ln & 15, kg = ln >> 4;
            bf16x8 v = *(const bf16x8*)(Pt + lr * 1032 + kq * 512 + s * 32 + kg * 8);
            *(bf16x8*)(dst + (size_t)c * 8) = v;
        }
    } else {
        // ---- edge weights: 65536 threads = B*N*K
        int tt = (bid - 320) * 256 + t;
        int bn = tt >> 4;
        int b  = bn >> 7;
        float2 ci = *(const float2*)(centre + (size_t)bn * 2);
        int j = nidx[tt];
        float2 cj = *(const float2*)(centre + (size_t)(b * N_ + j) * 2);
        float cx = ci.x - cj.x, cy = ci.y - cj.y;
        float rho = sqrtf(cx * cx + cy * cy);
        float theta = atan2f(cx, cy);            // atan2(x, y) per reference
        float w[KER];
        float sum = 0.f;
#pragma unroll
        for (int m = 0; m < KER; ++m) {
            float dr = rho - mr[m];
            float wr = expf(-0.5f * dr * dr / (1e-14f + pr[m] * pr[m]));
            float a1 = fabsf(theta - mt[m]);
            float a2 = fabsf(6.2831853071795864f - a1);
            float am = fminf(a1, a2);
            float wt = expf(-0.5f * am * am / (1e-14f + pt[m] * pt[m]));
            float wv = wr * wt;
            if (isnan(wv)) wv = 0.f;
            w[m] = wv;
            sum += wv;
        }
        float scale = gw[tt] / sum;
#pragma unroll
        for (int m = 0; m < KER; ++m) ew[(size_t)tt * KER + m] = w[m] * scale;
    }
}

// ---------------------------------------------------------------------------
// Fused kernel, block bid: b = bid&31, m = bid>>5 (bid%8 = b%8 -> XCD share).
// Zero-barrier split-K main loop; fragments loaded as CONTIGUOUS 1KB bursts
// from the packed layouts (no address divergence). Epilogue identical to R6.
// ---------------------------------------------------------------------------
__global__ __launch_bounds__(512, 2) void k_fused(const ushort* __restrict__ Fpack,
                                                  const ushort* __restrict__ Wpack,
                                                  const float* __restrict__ ew,
                                                  const int* __restrict__ nidx,
                                                  float* __restrict__ out) {
    __shared__ float Gt[128 * 132];               // 67584 B

    int tid  = threadIdx.x;
    int wave = tid >> 6;
    int lane = tid & 63;
    int kq = wave >> 2;            // K-half (0,1)
    int rh = (wave >> 1) & 1;      // 64-row half
    int ch = wave & 1;             // 64-col half
    int lr = lane & 15;
    int kg = lane >> 4;
    int bid = blockIdx.x;
    int b = bid & 31;
    int m = bid >> 5;

    // per-fragment bases (ushort offsets); s-step adds s*512
    const ushort* Abase[4];
    const ushort* Bbase[4];
#pragma unroll
    for (int i = 0; i < 4; ++i) {
        Abase[i] = Fpack + ((size_t)(b * 8 + rh * 4 + i) * 16384 + kq * 8192 + lane * 8);
        Bbase[i] = Wpack + ((size_t)(m * 8 + ch * 4 + i) * 16384 + kq * 8192 + lane * 8);
    }

    f32x4 acc[4][4];
#pragma unroll
    for (int i = 0; i < 4; ++i)
#pragma unroll
        for (int j = 0; j < 4; ++j) acc[i][j] = (f32x4){0.f, 0.f, 0.f, 0.f};

    // ---- main loop: 16 steps x {8 contiguous 16B frag loads + 16 MFMA}, no sync
#pragma unroll
    for (int s = 0; s < 16; ++s) {
        bf16x8 av[4], bv[4];
#pragma unroll
        for (int i = 0; i < 4; ++i) {
            av[i] = *(const bf16x8*)(Abase[i] + s * 512);
            bv[i] = *(const bf16x8*)(Bbase[i] + s * 512);
        }
#pragma unroll
        for (int mi = 0; mi < 4; ++mi)
#pragma unroll
            for (int nj = 0; nj < 4; ++nj)
                acc[mi][nj] = __builtin_amdgcn_mfma_f32_16x16x32_bf16(
                    av[mi], bv[nj], acc[mi][nj], 0, 0, 0);
    }

    // ---- gather metadata prefetch
    int n = tid >> 2, q = tid & 3;
    const int* ip = nidx + (size_t)(b * N_ + n) * KNB;
    int4 jv0 = *(const int4*)(ip);
    int4 jv1 = *(const int4*)(ip + 4);
    int4 jv2 = *(const int4*)(ip + 8);
    int4 jv3 = *(const int4*)(ip + 12);
    const float* ep = ew + (size_t)(b * N_ + n) * (KNB * KER) + m;
    float wv[KNB];
#pragma unroll
    for (int k = 0; k < KNB; ++k) wv[k] = ep[k * KER];

    // ---- split-K reduction into Gt (C/D layout: row=kg*4+r, col=lane&15)
    if (kq == 0) {
#pragma unroll
        for (int mi = 0; mi < 4; ++mi)
#pragma unroll
            for (int nj = 0; nj < 4; ++nj)
#pragma unroll
                for (int r = 0; r < 4; ++r) {
                    int grow = rh * 64 + mi * 16 + kg * 4 + r;
                    int gcol = ch * 64 + nj * 16 + lr;
                    Gt[grow * 132 + gcol] = acc[mi][nj][r];
                }
    }
    __syncthreads();
    if (kq == 1) {
#pragma unroll
        for (int mi = 0; mi < 4; ++mi)
#pragma unroll
            for (int nj = 0; nj < 4; ++nj)
#pragma unroll
                for (int r = 0; r < 4; ++r) {
                    int grow = rh * 64 + mi * 16 + kg * 4 + r;
                    int gcol = ch * 64 + nj * 16 + lr;
                    Gt[grow * 132 + gcol] += acc[mi][nj][r];
                }
    }
    __syncthreads();

    // ---- gather + ReLU: thread = (row n, quarter q, 32 cols)
    int rot[8];
#pragma unroll
    for (int i = 0; i < 8; ++i) rot[i] = (q * 4 + i * 4) & 31;
    f32x4 o[8];
#pragma unroll
    for (int i = 0; i < 8; ++i) o[i] = (f32x4){0.f, 0.f, 0.f, 0.f};
    int jarr[KNB] = {jv0.x, jv0.y, jv0.z, jv0.w, jv1.x, jv1.y, jv1.z, jv1.w,
                     jv2.x, jv2.y, jv2.z, jv2.w, jv3.x, jv3.y, jv3.z, jv3.w};
#pragma unroll
    for (int k = 0; k < KNB; ++k) {
        const float* gr = Gt + jarr[k] * 132 + q * 32;
        float w = wv[k];
#pragma unroll
        for (int i = 0; i < 8; ++i) {
            f32x4 v = *(const f32x4*)(gr + rot[i]);
            o[i] += v * w;
        }
    }
    float* op = out + (size_t)(b * N_ + n) * OUTC + m * DOUT + q * 32;
#pragma unroll
    for (int i = 0; i < 8; ++i) {
        f32x4 r = o[i];
#pragma unroll
        for (int jj = 0; jj < 4; ++jj) r[jj] = fmaxf(r[jj], 0.f);
        *(f32x4*)(op + rot[i]) = r;
    }
}

// ---------------------------------------------------------------------------
extern "C" void kernel_launch(void* const* d_in, const int* in_sizes, int n_in,
                              void* d_out, int out_size, void* d_ws, size_t ws_size,
                              hipStream_t stream) {
    const float* node_feats      = (const float*)d_in[0];
    const float* node_centre     = (const float*)d_in[1];
    const int*   neighbor_idx    = (const int*)d_in[2];
    const float* graph_weights   = (const float*)d_in[3];
    const float* mean_rho        = (const float*)d_in[4];
    const float* mean_theta      = (const float*)d_in[5];
    const float* precision_rho   = (const float*)d_in[6];
    const float* precision_theta = (const float*)d_in[7];
    const float* conv_w          = (const float*)d_in[8];
    float* out = (float*)d_out;

    char* ws = (char*)d_ws;
    ushort* Fpack = (ushort*)(ws);                   // 8 MB
    ushort* Wpack = (ushort*)(ws + (8u  << 20));     // 2 MB
    float*  ew    = (float*) (ws + (10u << 20));     // 2 MB

    k_prep<<<576, 256, 0, stream>>>(node_feats, Fpack, conv_w, Wpack,
                                    node_centre, neighbor_idx, graph_weights,
                                    mean_rho, mean_theta,
                                    precision_rho, precision_theta, ew);
    // 256 blocks; bid = m*32 + b so all 8 m-blocks of a batch land on one XCD
    k_fused<<<256, 512, 0, stream>>>(Fpack, Wpack, ew, neighbor_idx, out);
}